// Round 3
// baseline (231.415 us; speedup 1.0000x reference)
//
#include <hip/hip_runtime.h>
#include <math.h>

#define B_DIM 8
#define T_DIM 512
#define H_DIM 768
#define NTOK 511       // T - 1
#define NLAY 9         // 13 - LAYER_START
#define LAYER_START 4
#define NBAND 35       // pairs with |i-j| <= 4 (all that's needed)
#define CHUNKS 256     // blocks per b; 2 tokens per block (half-H per wave)
#define HHALF 384      // H_DIM / 2 per wave

// Per-block partial outputs and per-block var sums. Module globals so we never
// depend on d_ws. Every element is overwritten by wk_a before wk_r reads it,
// so 0xAA poisoning / stale state across calls is irrelevant. No atomics.
__device__ float g_part[B_DIM * CHUNKS * H_DIM];  // 6.3 MB
__device__ float g_varp[B_DIM * CHUNKS];

// banded Gram index: pair (lo, lo+d), d<=4 -> off(d)+lo, off(d)=9d-d(d-1)/2
#define BOFF(d) ((d)*9 - (d) * ((d)-1) / 2)

// DPP move: returns the dpp-selected lane's value (0 for invalid lanes).
// VALU-pipe cross-lane — no DS pipe, no lgkmcnt round trip.
template <int CTRL>
__device__ __forceinline__ float dpp_mov(float x) {
  return __builtin_bit_cast(
      float, __builtin_amdgcn_update_dpp(0, __builtin_bit_cast(int, x), CTRL,
                                         0xF, 0xF, true));
}

// Full-wave (64-lane) sum via gfx9 DPP ladder; total lands in lane 63.
__device__ __forceinline__ float wave_sum_dpp(float x) {
  x += dpp_mov<0x111>(x);  // row_shr:1
  x += dpp_mov<0x112>(x);  // row_shr:2
  x += dpp_mov<0x114>(x);  // row_shr:4
  x += dpp_mov<0x118>(x);  // row_shr:8  -> lane 15 of each row = row sum
  x += dpp_mov<0x142>(x);  // row_bcast:15 -> lane31 = S0+S1, lane63 = S2+S3
  x += dpp_mov<0x143>(x);  // row_bcast:31 -> lane63 = S0+S1+S2+S3
  return x;
}

// HALF-H SPLIT (R3): one token = TWO waves, 384 dims each. v[] drops 108->54
// VGPRs so the natural allocation should land <=128 -> 4 waves/SIMD (16/CU,
// 4 co-resident blocks) instead of 2/SIMD. R2's wk_a was ~25 µs vs an 18 µs
// HBM floor because 2 coarse block-generations left HBM idle during each
// generation's compute tail. NO min-waves cap: R1 proved a forced cap spills
// v wholesale (WRITE_SIZE 3 MB -> 114 MB). If VGPR_Count lands >128 this is
// expected ~neutral vs R2.
__global__ __launch_bounds__(256, 2) void wk_a(const float* __restrict__ ahs) {
  const int chunk = blockIdx.x;
  const int b = blockIdx.y;
  const int wave = threadIdx.x >> 6;   // 0..3
  const int lane = threadIdx.x & 63;
  const int slot = wave >> 1;          // token slot in block: 0..1
  const int half = wave & 1;           // which 384-dim half
  const int pb = wave & ~1;            // partner-pair base wave index
  const int t_raw = chunk * 2 + slot;
  const bool active = (t_raw < NTOK);
  const int t = active ? t_raw : (NTOK - 1);  // clamp: loads stay in bounds

  __shared__ float sG[4][36];          // per-wave banded Gram partials
  __shared__ float lds_out[2][H_DIM];  // per-token contribution
  __shared__ float lds_var[2];

  const size_t LSTR = (size_t)B_DIM * T_DIM * H_DIM;  // layer stride (floats)
  const float* base0 = ahs + (size_t)LAYER_START * LSTR +
                       ((size_t)b * T_DIM + t) * H_DIM + half * HHALF;

  // ---- load 9 layers x 6 floats/lane (float4 + float2), coalesced ----
  float4 v4[NLAY];
  float2 v2[NLAY];
#pragma unroll
  for (int l = 0; l < NLAY; ++l) {
    const float* base = base0 + (size_t)l * LSTR;
    v4[l] = *reinterpret_cast<const float4*>(base + lane * 4);
    v2[l] = *reinterpret_cast<const float2*>(base + 256 + lane * 2);
  }

  // ---- banded 9x9 Gram over this wave's 384 dims, per diagonal d ----
#pragma unroll
  for (int d = 0; d <= 4; ++d) {
    float gd[NLAY];
#pragma unroll
    for (int i = 0; i + d < NLAY; ++i) {
      const float4 x4 = v4[i], y4 = v4[i + d];
      const float2 x2 = v2[i], y2 = v2[i + d];
      gd[i] = x4.x * y4.x + x4.y * y4.y + x4.z * y4.z + x4.w * y4.w +
              x2.x * y2.x + x2.y * y2.y;
    }
    // DPP wave reduction (VALU pipe only); totals land in lane 63
#pragma unroll
    for (int i = 0; i + d < NLAY; ++i) gd[i] = wave_sum_dpp(gd[i]);
    if (lane == 63) {
#pragma unroll
      for (int i = 0; i + d < NLAY; ++i) sG[wave][BOFF(d) + i] = gd[i];
    }
  }
  __syncthreads();  // cross-wave: pair partials must be visible

  // Combined Gram value: sum of the token's two half-wave partials.
  auto SC = [&](int idx) -> float { return sG[pb][idx] + sG[pb + 1][idx]; };

  // ---- per-lane k: window rows + Cholesky (R = upper chol of Gram == QR's R
  //      up to row signs, which provably cancel in align/novelty) ----
  const int k = lane < NLAY ? lane : NLAY - 1;
  const int nl = (k >= 2) ? 2 : 0;
  const int nrr = (NLAY - 1 - k) < 2 ? (NLAY - 1 - k) : 2;
  const int m = nl + nrr + 1;  // 3..5, self row last

  auto rowf = [&](int i) -> int {
    return (i < nl) ? (k - 2 + i) : ((i < nl + nrr) ? (k + 1 + i - nl) : k);
  };
  auto GK = [&](int i, int j) -> float {
    int a = rowf(i), c = rowf(j);
    int lo = a < c ? a : c;
    int d = (a < c ? c : a) - lo;  // 0..4 always (window span <= 4)
    return SC(d * 9 - d * (d - 1) / 2 + lo);
  };

  float R[5][5];
#pragma unroll
  for (int j = 0; j < 5; ++j)
#pragma unroll
    for (int i = 0; i < 5; ++i) R[i][j] = 0.f;

#pragma unroll
  for (int j = 0; j < 5; ++j) {
    if (j < m) {
#pragma unroll
      for (int i = 0; i < 5; ++i) {
        if (i < j) {  // compile-time after unroll
          float s = GK(i, j);
#pragma unroll
          for (int p = 0; p < 4; ++p)
            if (p < i) s -= R[p][i] * R[p][j];
          R[i][j] = s / R[i][i];
        }
      }
      float sjj = GK(j, j);
#pragma unroll
      for (int p = 0; p < 4; ++p)
        if (p < j) sjj -= R[p][j] * R[p][j];
      R[j][j] = sqrtf(fmaxf(sjj, 0.f));
    }
  }

  // r = R[:, m-1]
  float r[5];
#pragma unroll
  for (int i = 0; i < 5; ++i)
    r[i] = (m == 3) ? R[i][2] : ((m == 4) ? R[i][3] : R[i][4]);

  // column-normalize Rsub = R[:m-1,:m-1], row means
  float rowmean[4] = {0.f, 0.f, 0.f, 0.f};
#pragma unroll
  for (int j = 0; j < 4; ++j) {
    if (j < m - 1) {
      float cn = 0.f;
#pragma unroll
      for (int i = 0; i < 4; ++i)
        if (i <= j) cn += R[i][j] * R[i][j];
      cn = fmaxf(sqrtf(cn), 1e-12f);
      float inv = 1.f / cn;
#pragma unroll
      for (int i = 0; i < 4; ++i)
        if (i < m - 1) rowmean[i] += R[i][j] * inv;
    }
  }

  const float inv_m1 = 1.f / (float)(m - 1);
  float dotv = 0.f, nrm2 = 0.f;
#pragma unroll
  for (int i = 0; i < 4; ++i) {
    if (i < m - 1) {
      dotv += (rowmean[i] * inv_m1) * r[i];
      nrm2 += r[i] * r[i];
    }
  }
  float align_raw = dotv / sqrtf(nrm2);
  float align_v = 1.f / (align_raw * (float)m * 2.f);
  float rlast = (m == 3) ? r[2] : ((m == 4) ? r[3] : r[4]);
  float nov_v = fabsf(rlast) / sqrtf(nrm2 + rlast * rlast);

  // ---- alphas from lanes 0..8: low-register two-pass shfl version ----
  float asum = 0.f, nsum = 0.f;
#pragma unroll
  for (int l = 0; l < NLAY; ++l) {
    asum += __shfl(align_v, l, 64);
    nsum += __shfl(nov_v, l, 64);
  }
  float c[NLAY];
  float csum = 0.f;
#pragma unroll
  for (int l = 0; l < NLAY; ++l) {
    float a = __shfl(align_v, l, 64) / asum + __shfl(nov_v, l, 64) / nsum;
    c[l] = a;
    csum += a;
  }

  // ---- adjacent-layer cosine sims -> sample variance (ddof=1) ----
  float sims[NLAY - 1];
  float smean = 0.f;
#pragma unroll
  for (int j = 0; j < NLAY - 1; ++j) {
    float num = SC(BOFF(1) + j);
    float den = fmaxf(sqrtf(SC(j)) * sqrtf(SC(j + 1)), 1e-8f);
    sims[j] = num / den;
    smean += sims[j];
  }
  smean *= (1.f / 8.f);
  float var = 0.f;
#pragma unroll
  for (int j = 0; j < NLAY - 1; ++j) {
    float d = sims[j] - smean;
    var += d * d;
  }
  var *= (1.f / 7.f);
  if (!active) var = 0.f;  // inactive token contributes exactly zero

  if (lane == 0 && half == 0) lds_var[slot] = var;

  // ---- weighted layer sum from register-resident v (no second read) ----
  const float scale = var / csum;
#pragma unroll
  for (int l = 0; l < NLAY; ++l) c[l] *= scale;

  float4 o4;
  o4.x = 0.f; o4.y = 0.f; o4.z = 0.f; o4.w = 0.f;
  float2 o2;
  o2.x = 0.f; o2.y = 0.f;
#pragma unroll
  for (int l = 0; l < NLAY; ++l) {
    o4.x += c[l] * v4[l].x;
    o4.y += c[l] * v4[l].y;
    o4.z += c[l] * v4[l].z;
    o4.w += c[l] * v4[l].w;
    o2.x += c[l] * v2[l].x;
    o2.y += c[l] * v2[l].y;
  }
  *reinterpret_cast<float4*>(&lds_out[slot][half * HHALF + lane * 4]) = o4;
  *reinterpret_cast<float2*>(&lds_out[slot][half * HHALF + 256 + lane * 2]) =
      o2;
  __syncthreads();  // cross-wave dependency: required

  // ---- cross-token sum, one partial vector + one partial var per block ----
  float* dst = g_part + ((size_t)(b * CHUNKS + chunk)) * H_DIM;
#pragma unroll
  for (int s = 0; s < 3; ++s) {
    int h = s * 256 + threadIdx.x;
    dst[h] = lds_out[0][h] + lds_out[1][h];
  }
  if (threadIdx.x == 0) {
    g_varp[b * CHUNKS + chunk] = lds_var[0] + lds_var[1];
  }
}

// grid = (3, B_DIM) x 256 threads: reduce 256 partials, divide by Ssum, write.
// ssum computed in PARALLEL (256 threads + DPP reduce + LDS combine); acc
// loop unrolls 16-deep — wk_r is latency-bound (24 blocks on 256 CUs).
__global__ __launch_bounds__(256) void wk_r(float* __restrict__ out) {
  const int b = blockIdx.y;
  const int tid = threadIdx.x;
  const int h = blockIdx.x * 256 + tid;

  __shared__ float s_ws[4];
  float vs = g_varp[b * CHUNKS + tid];  // tid in [0,256) == CHUNKS
  vs = wave_sum_dpp(vs);  // lane 63 of each wave holds that wave's total
  if ((tid & 63) == 63) s_ws[tid >> 6] = vs;
  __syncthreads();
  const float ssum = s_ws[0] + s_ws[1] + s_ws[2] + s_ws[3];

  float acc = 0.f;
#pragma unroll 16
  for (int j = 0; j < CHUNKS; ++j)
    acc += g_part[((size_t)(b * CHUNKS + j)) * H_DIM + h];

  out[b * H_DIM + h] = acc / ssum;
}

extern "C" void kernel_launch(void* const* d_in, const int* in_sizes, int n_in,
                              void* d_out, int out_size, void* d_ws, size_t ws_size,
                              hipStream_t stream) {
  const float* ahs = (const float*)d_in[0];
  // d_in[1] = attention_mask: unused by the reference computation
  float* out = (float*)d_out;
  (void)d_ws; (void)ws_size;

  wk_a<<<dim3(CHUNKS, B_DIM), dim3(256), 0, stream>>>(ahs);
  wk_r<<<dim3(3, B_DIM), dim3(256), 0, stream>>>(out);
}